// Round 16
// baseline (116.867 us; speedup 1.0000x reference)
//
#include <hip/hip_runtime.h>
#include <hip/hip_bf16.h>
#include <math.h>

#define BB 2
#define II 256
#define DD 768
#define HH 12
#define DPP 128
#define NPQ 4
#define NPV 8
#define FEAT_DIM 2304
#define NPACK 3456

// ---------------- workspace layout (float units) ----------------
#define OFF_QKVPTS ((size_t)0)         // [512][3456] f32 (only cols >=2304 written)
#define OFF_PBATTN ((size_t)1769472)   // [b][h][i][j] bf16 (pb+bias)
#define OFF_X1DB   ((size_t)3342336)   // [512][768] bf16 (dead after gemm1)
#define OFF_VT     OFF_X1DB            // [2][768][256] bf16 (overlay)
#define OFF_W1T    ((size_t)3538944)   // [3456][768] bf16 (dead after gemm1)
#define OFF_ABF    OFF_W1T             // [b][h][i][j] bf16 attn (overlay)
#define OFF_W2T    ((size_t)4866048)   // [768][2304] bf16
#define OFF_FEATB  ((size_t)5750784)   // [512][2304] bf16
#define OFF_QPTS   ((size_t)6340608)   // [b][h][i][24] f32
#define OFF_KPTS   ((size_t)6488064)   // [b][h][24][256] f32
#define OFF_QKHM   ((size_t)6635520)   // [2][2][12][256][64] bf16
#define OFF_VGJT   ((size_t)7028736)   // [2][576][256] bf16
#define OFF_WPVT   ((size_t)7176192)   // [768][128] bf16
// end = 7,225,344 f = 28.9 MB

#define SCALAR_W 0.07216878364870323f
#define POINT_W  0.13608276348795434f
#define PAIR_W   0.57735026918962576f

typedef __attribute__((ext_vector_type(8))) short short8;
typedef __attribute__((ext_vector_type(4))) short short4v;
typedef __attribute__((ext_vector_type(4))) float f32x4;

__device__ inline ushort f2bf(float f) {
  __hip_bfloat16 h = __float2bfloat16(f);
  return *reinterpret_cast<ushort*>(&h);
}
__device__ inline float bf2f(short u) {
  return __uint_as_float(((unsigned int)(unsigned short)u) << 16);
}

// ---------- merged prep: pairbias (2048) | convert_x (192) | 11 transposes ----------
struct TJob { const float* src; ushort* dst; int K, N, sStride, dStride, nx, ny; };
struct TJobs { TJob j[11]; };

__global__ __launch_bounds__(256)
void prep_kernel(const float* __restrict__ x2d, const float* __restrict__ Wpb,
                 const float* __restrict__ bias, ushort* __restrict__ pbattn,
                 const float* __restrict__ x1d, ushort* __restrict__ x1db,
                 TJobs jobs) {
  __shared__ __align__(16) char smem[9216];
  const int blk = blockIdx.x;
  const int tid = threadIdx.x;
  if (blk < 2048) {
    // ---- pair-bias: MFMA, A direct from global x2d; 64 j-rows/block ----
    ushort* wpbT_s = (ushort*)smem;                 // 16*136*2 = 4352
    ushort* pb_s   = (ushort*)(smem + 4352);        // 64*18*2 = 2304
    const int bi = blk >> 2, quarter = blk & 3;
    const int b = bi >> 8, i = bi & 255;
    for (int u = tid; u < 2048; u += 256) {
      const int h = u >> 7, p = u & 127;
      wpbT_s[h * 136 + p] = (h < 12) ? f2bf(Wpb[p * 12 + h]) : (ushort)0;
    }
    __syncthreads();
    const int lane = tid & 63, w = tid >> 6;
    const int l15 = lane & 15, kq = lane >> 4;
    const float* xbase = x2d + ((size_t)bi * II + quarter * 64) * DPP;
    {
      const int jl = w * 16 + l15;
      const float* arow = xbase + (size_t)jl * DPP;
      f32x4 acc = {};
#pragma unroll
      for (int kk = 0; kk < 4; ++kk) {
        const float4 f0 = *reinterpret_cast<const float4*>(arow + kk * 32 + kq * 8);
        const float4 f1 = *reinterpret_cast<const float4*>(arow + kk * 32 + kq * 8 + 4);
        short8 af;
        af[0] = (short)f2bf(f0.x); af[1] = (short)f2bf(f0.y);
        af[2] = (short)f2bf(f0.z); af[3] = (short)f2bf(f0.w);
        af[4] = (short)f2bf(f1.x); af[5] = (short)f2bf(f1.y);
        af[6] = (short)f2bf(f1.z); af[7] = (short)f2bf(f1.w);
        const short8 bf = *reinterpret_cast<const short8*>(&wpbT_s[l15 * 136 + kk * 32 + kq * 8]);
        acc = __builtin_amdgcn_mfma_f32_16x16x32_bf16(af, bf, acc, 0, 0, 0);
      }
#pragma unroll
      for (int rr = 0; rr < 4; ++rr)
        pb_s[(w * 16 + kq * 4 + rr) * 18 + l15] = f2bf(acc[rr]);
    }
    __syncthreads();
    if (tid < 96) {
      const int h = tid >> 3, jq = tid & 7;
      const int jl0 = jq * 8;
      const size_t base = (((size_t)(b * HH + h) * II + i) * II) + quarter * 64 + jl0;
      const float4 bv0 = *reinterpret_cast<const float4*>(bias + base);
      const float4 bv1 = *reinterpret_cast<const float4*>(bias + base + 4);
      const float bv[8] = {bv0.x, bv0.y, bv0.z, bv0.w, bv1.x, bv1.y, bv1.z, bv1.w};
      short8 o;
#pragma unroll
      for (int e = 0; e < 8; ++e)
        o[e] = (short)f2bf(PAIR_W * bf2f((short)pb_s[(jl0 + e) * 18 + h]) + bv[e]);
      *reinterpret_cast<short8*>(pbattn + base) = o;
    }
  } else if (blk < 2240) {
    // ---- x1d -> bf16 ----
    const int idx = (blk - 2048) * 256 + tid;
    if (idx < 512 * 768 / 8) {
      const float4 f0 = reinterpret_cast<const float4*>(x1d)[idx * 2 + 0];
      const float4 f1 = reinterpret_cast<const float4*>(x1d)[idx * 2 + 1];
      short8 v;
      v[0] = (short)f2bf(f0.x); v[1] = (short)f2bf(f0.y);
      v[2] = (short)f2bf(f0.z); v[3] = (short)f2bf(f0.w);
      v[4] = (short)f2bf(f1.x); v[5] = (short)f2bf(f1.y);
      v[6] = (short)f2bf(f1.z); v[7] = (short)f2bf(f1.w);
      reinterpret_cast<short8*>(x1db)[idx] = v;
    }
  } else {
    // ---- weight transpose jobs (flat-dispatched) ----
    float (*t)[33] = (float(*)[33])smem;
    int blk2 = blk - 2240;
#pragma unroll 1
    for (int jj = 0; jj < 11; ++jj) {
      const TJob J = jobs.j[jj];
      const int cnt = J.nx * J.ny;
      if (blk2 < cnt) {
        const int n0 = (blk2 % J.nx) * 32, k0 = (blk2 / J.nx) * 32;
        const int c = tid & 31, r = tid >> 5;
#pragma unroll
        for (int u = 0; u < 4; ++u) {
          const int kk = r + u * 8;
          t[kk][c] = (n0 + c < J.N) ? J.src[(size_t)(k0 + kk) * J.sStride + n0 + c] : 0.f;
        }
        __syncthreads();
#pragma unroll
        for (int u = 0; u < 4; ++u) {
          const int n = n0 + r + u * 8;
          if (n < J.N) J.dst[(size_t)n * J.dStride + k0 + c] = f2bf(t[c][r + u * 8]);
        }
        return;
      }
      blk2 -= cnt;
    }
  }
}

// ---------- MFMA bf16 GEMM (gemm1: epilogue routing; gemm2: plain) ----------
__global__ __launch_bounds__(256)
void mfma_gemm_kernel(const ushort* __restrict__ A, const ushort* __restrict__ Bt,
                      float* __restrict__ C, const float* __restrict__ bias,
                      ushort* __restrict__ Cb, ushort* __restrict__ Vt, int N, int K) {
  __shared__ short a_s[64 * 64];
  __shared__ short b_s[64 * 64];
  const int tid = threadIdx.x;
  const int lane = tid & 63;
  const int wave = tid >> 6;
  const int wm = wave >> 1, wn = wave & 1;
  const int m0 = blockIdx.x * 64, n0 = blockIdx.y * 64;
  const int lrow = tid >> 3, lch = tid & 7;
  const int l15 = lane & 15, l7 = lane & 7, kq = lane >> 4;
  f32x4 acc[2][2] = {};
  for (int kc = 0; kc < K; kc += 64) {
#pragma unroll
    for (int u = 0; u < 2; ++u) {
      const int r = lrow + u * 32;
      const short8 av = *reinterpret_cast<const short8*>(A  + (size_t)(m0 + r) * K + kc + lch * 8);
      const short8 bv = *reinterpret_cast<const short8*>(Bt + (size_t)(n0 + r) * K + kc + lch * 8);
      const int sc = ((lch ^ (r & 7)) << 3);
      *reinterpret_cast<short8*>(&a_s[r * 64 + sc]) = av;
      *reinterpret_cast<short8*>(&b_s[r * 64 + sc]) = bv;
    }
    __syncthreads();
#pragma unroll
    for (int kk = 0; kk < 64; kk += 32) {
      const int ch = (kk >> 3) + kq;
      const int cx = ((ch ^ l7) << 3);
      short8 af[2], bf[2];
      af[0] = *reinterpret_cast<const short8*>(&a_s[(wm * 32 +      l15) * 64 + cx]);
      af[1] = *reinterpret_cast<const short8*>(&a_s[(wm * 32 + 16 + l15) * 64 + cx]);
      bf[0] = *reinterpret_cast<const short8*>(&b_s[(wn * 32 +      l15) * 64 + cx]);
      bf[1] = *reinterpret_cast<const short8*>(&b_s[(wn * 32 + 16 + l15) * 64 + cx]);
#pragma unroll
      for (int mt = 0; mt < 2; ++mt)
#pragma unroll
        for (int nt = 0; nt < 2; ++nt)
          acc[mt][nt] = __builtin_amdgcn_mfma_f32_16x16x32_bf16(af[mt], bf[nt], acc[mt][nt], 0, 0, 0);
    }
    __syncthreads();
  }
#pragma unroll
  for (int mt = 0; mt < 2; ++mt) {
    const int r0 = m0 + wm * 32 + mt * 16 + kq * 4;
#pragma unroll
    for (int nt = 0; nt < 2; ++nt) {
      const int c = n0 + wn * 32 + nt * 16 + l15;
      const float bv = bias ? bias[c] : 0.f;
#pragma unroll
      for (int rr = 0; rr < 4; ++rr) {
        const float val = acc[mt][nt][rr] + bv;
        const int m = r0 + rr;
        if (!Cb) {
          C[(size_t)m * N + c] = val;
        } else if (c < 1536) {
          const int bb = m >> 8, ii = m & 255;
          const int plane = (c >= 768) ? 1 : 0;
          const int hh = (c & 767) >> 6, cc2 = c & 63;
          Cb[((((size_t)plane * BB + bb) * HH + hh) * II + ii) * 64 + cc2] = f2bf(val);
        } else if (c < 2304) {
          const int bb = m >> 8, ii = m & 255;
          Vt[((size_t)bb * DD + (c - 1536)) * II + ii] = f2bf(val);
        } else {
          C[(size_t)m * N + c] = val;
        }
      }
    }
  }
}

// ---------- frame transforms ----------
struct XfJob { const float* T; const float* R; float* dstf; ushort* dstb;
               int np; int sub; int srccol; int mode; };
struct XfJobs { XfJob j[6]; };

__global__ __launch_bounds__(256)
void transform_kernel(const float* __restrict__ qkvpts, XfJobs jobs) {
  const XfJob J = jobs.j[blockIdx.y];
  const int idx = blockIdx.x * 256 + threadIdx.x;
  if (J.mode == 1) {
    const int hn = HH * J.np;
    if (idx >= BB * II * hn) return;
    const int bi = idx / hn, rem = idx - bi * hn;
    const float* p = qkvpts + (size_t)bi * NPACK + J.srccol + rem * 3;
    const float p0 = p[0], p1 = p[1], p2 = p[2];
    const float* R = J.R + (size_t)bi * 9;
    const float* T = J.T + (size_t)bi * 3;
    const float o0 = R[0] * p0 + R[3] * p1 + R[6] * p2 + T[0];
    const float o1 = R[1] * p0 + R[4] * p1 + R[7] * p2 + T[1];
    const float o2 = R[2] * p0 + R[5] * p1 + R[8] * p2 + T[2];
    const int h = rem / J.np, n = rem - h * J.np;
    const int b = bi >> 8, i = bi & 255;
    float* d = J.dstf + ((size_t)(b * HH + h) * II + i) * 24 + J.sub + n * 3;
    d[0] = o0; d[1] = o1; d[2] = o2;
  } else {
    if (idx >= BB * HH * J.np * II) return;
    const int i = idx & 255;
    int r2 = idx >> 8;
    const int n = r2 % J.np; r2 /= J.np;
    const int h = r2 % HH;
    const int b = r2 / HH;
    const int bi = b * II + i;
    const float* p = qkvpts + (size_t)bi * NPACK + J.srccol + (h * J.np + n) * 3;
    const float p0 = p[0], p1 = p[1], p2 = p[2];
    const float* R = J.R + (size_t)bi * 9;
    const float* T = J.T + (size_t)bi * 3;
    const float o0 = R[0] * p0 + R[3] * p1 + R[6] * p2 + T[0];
    const float o1 = R[1] * p0 + R[4] * p1 + R[7] * p2 + T[1];
    const float o2 = R[2] * p0 + R[5] * p1 + R[8] * p2 + T[2];
    if (J.mode == 2) {
      const int col = J.sub + h * 24 + n * 3;
      ushort* d = J.dstb + ((size_t)b * 576 + col) * II + i;
      d[0] = f2bf(o0); d[II] = f2bf(o1); d[2 * II] = f2bf(o2);
    } else {
      float* d = J.dstf + ((size_t)(b * HH + h) * 24 + J.sub + n * 3) * II + i;
      d[0] = o0; d[II] = o1; d[2 * II] = o2;
    }
  }
}

// ---------- fused attention + av: logits/softmax, then attn @ [v|og] in-block ----------
__global__ __launch_bounds__(256)
void attn_av_kernel(const ushort* __restrict__ qkhm,
                    const float* __restrict__ qpts, const float* __restrict__ kpts,
                    const float* __restrict__ tpw_past, const float* __restrict__ tpw_last,
                    const ushort* __restrict__ pbattn, ushort* __restrict__ abf,
                    const ushort* __restrict__ vt, const ushort* __restrict__ vgjt,
                    const float* __restrict__ past_T, const float* __restrict__ past_R,
                    ushort* __restrict__ featb) {
  __shared__ float qp_s[16 * 24];
  __shared__ float pb_s[16 * 260];      // reused as c_s [16][120] after softmax
  __shared__ float red_s[2][16 * 4];
  __shared__ ushort a_lds[16 * 256];    // swizzled 8-chunks
  const int tid = threadIdx.x;
  const int lane = tid & 63;
  const int w = tid >> 6;
  const int i0 = blockIdx.x * 16;
  const int h = blockIdx.y;
  const int b = blockIdx.z;
  const size_t bh = (size_t)b * HH + h;
  if (tid < 96)
    reinterpret_cast<float4*>(qp_s)[tid] =
        reinterpret_cast<const float4*>(qpts + (bh * II + i0) * 24)[tid];
  {
    const ushort* src = pbattn + (bh * II + i0) * II;
    for (int u = tid; u < 512; u += 256) {
      const int r = u >> 5, c8 = u & 31;
      const short8 v = *reinterpret_cast<const short8*>(src + (size_t)r * II + c8 * 8);
      float* d = &pb_s[r * 260 + c8 * 8];
#pragma unroll
      for (int e = 0; e < 8; ++e) d[e] = bf2f(v[e]);
    }
  }
  __syncthreads();
  const int l15 = lane & 15, kq = lane >> 4;
  const ushort* qrow = qkhm + (((size_t)b * HH + h) * II + i0 + l15) * 64;
  const ushort* kplane = qkhm + (((size_t)(BB + b) * HH + h) * II) * 64;
  const short8 af0 = *reinterpret_cast<const short8*>(qrow + kq * 8);
  const short8 af1 = *reinterpret_cast<const short8*>(qrow + 32 + kq * 8);
  const float pwp = 0.5f * POINT_W * log1pf(expf(tpw_past[h]));
  const float pwl = 0.5f * POINT_W * log1pf(expf(tpw_last[h]));
  const float* kpt = kpts + bh * 6144;
  float lg[4][4];
#pragma unroll
  for (int jb = 0; jb < 4; ++jb) {
    const int j = w * 64 + jb * 16 + l15;
    const ushort* krow = kplane + (size_t)j * 64;
    f32x4 acc = {};
    acc = __builtin_amdgcn_mfma_f32_16x16x32_bf16(
        af0, *reinterpret_cast<const short8*>(krow + kq * 8), acc, 0, 0, 0);
    acc = __builtin_amdgcn_mfma_f32_16x16x32_bf16(
        af1, *reinterpret_cast<const short8*>(krow + 32 + kq * 8), acc, 0, 0, 0);
    float kg[24];
#pragma unroll
    for (int c = 0; c < 24; ++c) kg[c] = kpt[c * 256 + j];
#pragma unroll
    for (int rr = 0; rr < 4; ++rr) {
      const int il = kq * 4 + rr;
      const float* qg = &qp_s[il * 24];
      float dp = 0.f, dl = 0.f;
#pragma unroll
      for (int n = 0; n < 4; ++n) {
        float dx = qg[n * 3] - kg[n * 3], dy = qg[n * 3 + 1] - kg[n * 3 + 1],
              dz = qg[n * 3 + 2] - kg[n * 3 + 2];
        dp += sqrtf(dx * dx + dy * dy + dz * dz);
        dx = qg[12 + n * 3] - kg[12 + n * 3]; dy = qg[12 + n * 3 + 1] - kg[12 + n * 3 + 1];
        dz = qg[12 + n * 3 + 2] - kg[12 + n * 3 + 2];
        dl += sqrtf(dx * dx + dy * dy + dz * dz);
      }
      lg[jb][rr] = SCALAR_W * acc[rr] - pwp * dp - pwl * dl + pb_s[il * 260 + j];
    }
  }
#pragma unroll
  for (int rr = 0; rr < 4; ++rr) {
    float m = fmaxf(fmaxf(lg[0][rr], lg[1][rr]), fmaxf(lg[2][rr], lg[3][rr]));
    m = fmaxf(m, __shfl_xor(m, 1));
    m = fmaxf(m, __shfl_xor(m, 2));
    m = fmaxf(m, __shfl_xor(m, 4));
    m = fmaxf(m, __shfl_xor(m, 8));
    if (l15 == 0) red_s[0][(kq * 4 + rr) * 4 + w] = m;
  }
  __syncthreads();
#pragma unroll
  for (int rr = 0; rr < 4; ++rr) {
    const int il = kq * 4 + rr;
    const float* r = &red_s[0][il * 4];
    const float m = fmaxf(fmaxf(r[0], r[1]), fmaxf(r[2], r[3]));
    float s = 0.f;
#pragma unroll
    for (int jb = 0; jb < 4; ++jb) { lg[jb][rr] = __expf(lg[jb][rr] - m); s += lg[jb][rr]; }
    s += __shfl_xor(s, 1); s += __shfl_xor(s, 2);
    s += __shfl_xor(s, 4); s += __shfl_xor(s, 8);
    if (l15 == 0) red_s[1][il * 4 + w] = s;
  }
  __syncthreads();
#pragma unroll
  for (int rr = 0; rr < 4; ++rr) {
    const int il = kq * 4 + rr;
    const float* r = &red_s[1][il * 4];
    const float inv = 1.f / (r[0] + r[1] + r[2] + r[3]);
#pragma unroll
    for (int jb = 0; jb < 4; ++jb) {
      const int j = w * 64 + jb * 16 + l15;
      const int ch = j >> 3;
      a_lds[il * 256 + ((ch ^ (il & 7)) << 3) + (j & 7)] = f2bf(lg[jb][rr] * inv);
    }
  }
  __syncthreads();
  // coalesced global write of attn weights (for wpair)
  ushort* ab = abf + (bh * II + i0) * II;
#pragma unroll
  for (int u = 0; u < 2; ++u) {
    const int idx = tid + u * 256;
    const int r = idx >> 5, cc = idx & 31;
    *reinterpret_cast<short8*>(ab + (size_t)r * II + cc * 8) =
        *reinterpret_cast<const short8*>(&a_lds[r * 256 + ((cc ^ (r & 7)) << 3)]);
  }
  // ---- av part: C[16 i][112 c] = attn @ [v | og_past | og_last] ----
  float* c_s = pb_s;    // reuse (pb_s no longer needed); stride 120
  for (int t = w; t < 7; t += 4) {
    const int c = t * 16 + l15;   // 0..111
    const ushort* bcol;
    if (c < 64)      bcol = vt   + ((size_t)b * DD + h * 64 + c) * II;
    else if (c < 88) bcol = vgjt + ((size_t)b * 576 + h * 24 + (c - 64)) * II;
    else             bcol = vgjt + ((size_t)b * 576 + 288 + h * 24 + (c - 88)) * II;
    f32x4 acc = {};
#pragma unroll
    for (int ks = 0; ks < 8; ++ks) {
      const int ch = ks * 4 + kq;
      const short8 af = *reinterpret_cast<const short8*>(&a_lds[l15 * 256 + ((ch ^ (l15 & 7)) << 3)]);
      const short8 bf = *reinterpret_cast<const short8*>(bcol + ks * 32 + kq * 8);
      acc = __builtin_amdgcn_mfma_f32_16x16x32_bf16(af, bf, acc, 0, 0, 0);
    }
#pragma unroll
    for (int rr = 0; rr < 4; ++rr) c_s[(kq * 4 + rr) * 120 + c] = acc[rr];
  }
  __syncthreads();
  // epilogue 1: scalar part (16 i x 64 c)
  if (tid < 128) {
    const int il = tid >> 3, c0 = (tid & 7) * 8;
    ushort* fo = featb + (size_t)(b * II + i0 + il) * FEAT_DIM + 768 + h * 64 + c0;
    short8 o;
#pragma unroll
    for (int e = 0; e < 8; ++e) o[e] = (short)f2bf(c_s[il * 120 + c0 + e]);
    *reinterpret_cast<short8*>(fo) = o;
  }
  // epilogue 2: og inverse transform + norms (16 i x 2 br x 8 n)
  {
    const int u = tid;
    if (u < 256) {
      const int il = u >> 4;
      const int br = (u >> 3) & 1;
      const int n = u & 7;
      const int bi = b * II + i0 + il;
      const float* T = past_T + (size_t)bi * 3;
      const float* R = past_R + (size_t)bi * 9;
      const int cb = 64 + br * 24 + n * 3;
      const float o0 = c_s[il * 120 + cb + 0] - T[0];
      const float o1 = c_s[il * 120 + cb + 1] - T[1];
      const float o2 = c_s[il * 120 + cb + 2] - T[2];
      const float l0 = R[0] * o0 + R[1] * o1 + R[2] * o2;
      const float l1 = R[3] * o0 + R[4] * o1 + R[5] * o2;
      const float l2 = R[6] * o0 + R[7] * o1 + R[8] * o2;
      const float nn = sqrtf(l0 * l0 + l1 * l1 + l2 * l2);
      const int r = h * 8 + n;
      ushort* fout = featb + (size_t)bi * FEAT_DIM;
      const int olbase = br ? 1920 : 1536;
      const int nbase  = br ? 2208 : 1824;
      fout[olbase + r * 3 + 0] = f2bf(l0);
      fout[olbase + r * 3 + 1] = f2bf(l1);
      fout[olbase + r * 3 + 2] = f2bf(l2);
      fout[nbase + r] = f2bf(nn);
    }
  }
}

// ---------- wpair: in-LDS transpose of x2d (4 j-tiles), MFMA, then @ WpvT ----------
__global__ __launch_bounds__(256)
void wpair_kernel(const float* __restrict__ x2d, const ushort* __restrict__ abf,
                  const ushort* __restrict__ wpvt, ushort* __restrict__ featb) {
  __shared__ ushort a_s[16 * 256];
  __shared__ ushort tb[64 * 136];
  __shared__ float t_s[16][128];
  const int tid = threadIdx.x;
  const int bi = blockIdx.x;
  const int b = bi >> 8, i = bi & 255;
#pragma unroll
  for (int u = 0; u < 2; ++u) {
    const int c = tid + u * 256;
    const int h = c >> 5, ch = c & 31;
    short8 v = {};
    if (h < 12)
      v = *reinterpret_cast<const short8*>(abf + (((size_t)(b * HH + h) * II + i) * II) + ch * 8);
    *reinterpret_cast<short8*>(&a_s[h * 256 + ((ch ^ h) << 3)]) = v;
  }
  const int lane = tid & 63, w = tid >> 6;
  const int l15 = lane & 15, kq = lane >> 4;
  const int n0 = w * 32;
  f32x4 acc[2] = {};
  for (int jt = 0; jt < 4; ++jt) {
    __syncthreads();
    const float4* src = reinterpret_cast<const float4*>(x2d + ((size_t)bi * II + jt * 64) * DPP);
#pragma unroll
    for (int u = 0; u < 8; ++u) {
      const int fid = tid + u * 256;
      const int j = fid >> 5, p4 = (fid & 31) * 4;
      const float4 v = src[fid];
      short4v o;
      o[0] = (short)f2bf(v.x); o[1] = (short)f2bf(v.y);
      o[2] = (short)f2bf(v.z); o[3] = (short)f2bf(v.w);
      *reinterpret_cast<short4v*>(&tb[j * 136 + (p4 ^ ((j >> 3) << 4))]) = o;
    }
    __syncthreads();
#pragma unroll
    for (int nt = 0; nt < 2; ++nt) {
      const int p = n0 + nt * 16 + l15;
#pragma unroll
      for (int kk = 0; kk < 2; ++kk) {
        const int ch32 = jt * 8 + kk * 4 + kq;
        const short8 af = *reinterpret_cast<const short8*>(&a_s[l15 * 256 + ((ch32 ^ l15) << 3)]);
        short8 bf;
#pragma unroll
        for (int e = 0; e < 8; ++e) {
          const int row = kk * 32 + kq * 8 + e;
          bf[e] = (short)tb[row * 136 + (p ^ ((row >> 3) << 4))];
        }
        acc[nt] = __builtin_amdgcn_mfma_f32_16x16x32_bf16(af, bf, acc[nt], 0, 0, 0);
      }
    }
  }
#pragma unroll
  for (int nt = 0; nt < 2; ++nt) {
    const int p = n0 + nt * 16 + l15;
#pragma unroll
    for (int r = 0; r < 4; ++r) t_s[kq * 4 + r][p] = acc[nt][r];
  }
  __syncthreads();
  ushort* fout = featb + (size_t)bi * FEAT_DIM;
#pragma unroll
  for (int u = 0; u < 3; ++u) {
    const int c = tid + u * 256;
    const int h = c >> 6;
    const ushort* wr = wpvt + (size_t)c * DPP;
    float o = 0.f;
    for (int p = 0; p < DPP; p += 8) {
      const short8 wv = *reinterpret_cast<const short8*>(wr + p);
#pragma unroll
      for (int e = 0; e < 8; ++e) o += t_s[h][p + e] * bf2f(wv[e]);
    }
    fout[c] = f2bf(o);
  }
}

extern "C" void kernel_launch(void* const* d_in, const int* in_sizes, int n_in,
                              void* d_out, int out_size, void* d_ws, size_t ws_size,
                              hipStream_t stream) {
  (void)in_sizes; (void)n_in; (void)out_size; (void)ws_size;
  const float* x1d      = (const float*)d_in[0];
  const float* x2d      = (const float*)d_in[1];
  const float* past_T   = (const float*)d_in[2];
  const float* past_R   = (const float*)d_in[3];
  const float* last_T   = (const float*)d_in[4];
  const float* last_R   = (const float*)d_in[5];
  const float* bias     = (const float*)d_in[6];
  const float* Wq       = (const float*)d_in[7];
  const float* Wk       = (const float*)d_in[8];
  const float* Wv       = (const float*)d_in[9];
  const float* Wpb      = (const float*)d_in[10];
  const float* Wpq_past = (const float*)d_in[11];
  const float* Wpk_past = (const float*)d_in[12];
  const float* Wpv_past = (const float*)d_in[13];
  const float* Wpq_last = (const float*)d_in[14];
  const float* Wpk_last = (const float*)d_in[15];
  const float* Wpv_last = (const float*)d_in[16];
  const float* tpw_past = (const float*)d_in[17];
  const float* tpw_last = (const float*)d_in[18];
  const float* W_pair_value = (const float*)d_in[19];
  const float* W_out    = (const float*)d_in[20];
  const float* b_out    = (const float*)d_in[21];
  float* out = (float*)d_out;
  float* ws  = (float*)d_ws;

  float*  qkvpts = ws + OFF_QKVPTS;
  ushort* pbattn = (ushort*)(ws + OFF_PBATTN);
  ushort* x1db   = (ushort*)(ws + OFF_X1DB);
  ushort* vt     = (ushort*)(ws + OFF_VT);
  ushort* w1t    = (ushort*)(ws + OFF_W1T);
  ushort* abf    = (ushort*)(ws + OFF_ABF);
  ushort* w2t    = (ushort*)(ws + OFF_W2T);
  ushort* featb  = (ushort*)(ws + OFF_FEATB);
  float*  qpts   = ws + OFF_QPTS;
  float*  kpts   = ws + OFF_KPTS;
  ushort* qkhm   = (ushort*)(ws + OFF_QKHM);
  ushort* vgjt   = (ushort*)(ws + OFF_VGJT);
  ushort* wpvt   = (ushort*)(ws + OFF_WPVT);

  const dim3 blk256(256);

  // 1) merged prep: pairbias (2048 blk) | x1d->bf16 | 11 weight transposes
  {
    TJobs jobs = {};
    jobs.j[0]  = {Wq,       w1t + (size_t)   0 * 768, DD,      DD,   DD,  768,  24, 24};
    jobs.j[1]  = {Wk,       w1t + (size_t) 768 * 768, DD,      DD,   DD,  768,  24, 24};
    jobs.j[2]  = {Wv,       w1t + (size_t)1536 * 768, DD,      DD,   DD,  768,  24, 24};
    jobs.j[3]  = {Wpq_past, w1t + (size_t)2304 * 768, DD,     144,   144, 768,   5, 24};
    jobs.j[4]  = {Wpk_past, w1t + (size_t)2448 * 768, DD,     144,   144, 768,   5, 24};
    jobs.j[5]  = {Wpv_past, w1t + (size_t)2592 * 768, DD,     288,   288, 768,   9, 24};
    jobs.j[6]  = {Wpq_last, w1t + (size_t)2880 * 768, DD,     144,   144, 768,   5, 24};
    jobs.j[7]  = {Wpk_last, w1t + (size_t)3024 * 768, DD,     144,   144, 768,   5, 24};
    jobs.j[8]  = {Wpv_last, w1t + (size_t)3168 * 768, DD,     288,   288, 768,   9, 24};
    jobs.j[9]  = {W_out,    w2t,                      FEAT_DIM, DD,  DD,  2304, 24, 72};
    jobs.j[10] = {W_pair_value, wpvt,                 DPP,     DD,   DD,  DPP,  24,  4};
    int tblocks = 0;
    for (int j = 0; j < 11; ++j) tblocks += jobs.j[j].nx * jobs.j[j].ny;
    prep_kernel<<<dim3(2240 + tblocks), blk256, 0, stream>>>(
        x2d, Wpb, bias, pbattn, x1d, x1db, jobs);
  }

  // 2) fused GEMM: qk -> qkhm, v -> vt, points -> qkvpts f32
  mfma_gemm_kernel<<<dim3(8, 54), blk256, 0, stream>>>(
      x1db, w1t, qkvpts, nullptr, qkhm, vt, NPACK, DD);

  // 3) frame transforms
  {
    XfJobs jobs = {};
    jobs.j[0] = {past_T, past_R, qpts, nullptr, NPQ,   0, 2304, 1};
    jobs.j[1] = {past_T, past_R, kpts, nullptr, NPQ,   0, 2448, 3};
    jobs.j[2] = {past_T, past_R, nullptr, vgjt, NPV,   0, 2592, 2};
    jobs.j[3] = {last_T, last_R, qpts, nullptr, NPQ,  12, 2880, 1};
    jobs.j[4] = {last_T, last_R, kpts, nullptr, NPQ,  12, 3024, 3};
    jobs.j[5] = {last_T, last_R, nullptr, vgjt, NPV, 288, 3168, 2};
    transform_kernel<<<dim3(192, 6), blk256, 0, stream>>>(qkvpts, jobs);
  }

  // 4) fused attention + av
  attn_av_kernel<<<dim3(16, HH, BB), blk256, 0, stream>>>(
      qkhm, qpts, kpts, tpw_past, tpw_last, pbattn, abf,
      vt, vgjt, past_T, past_R, featb);

  // 5) wpair (512 blocks)
  wpair_kernel<<<dim3(BB * II), blk256, 0, stream>>>(x2d, abf, wpvt, featb);

  // 6) out = feat @ W_out + b_out
  mfma_gemm_kernel<<<dim3(8, 12), blk256, 0, stream>>>(
      featb, w2t, out, b_out, nullptr, nullptr, DD, FEAT_DIM);
}

// Round 17
// 115.105 us; speedup vs baseline: 1.0153x; 1.0153x over previous
//
#include <hip/hip_runtime.h>
#include <hip/hip_bf16.h>
#include <math.h>

#define BB 2
#define II 256
#define DD 768
#define HH 12
#define DPP 128
#define NPQ 4
#define NPV 8
#define FEAT_DIM 2304
#define NPACK 3456

// ---------------- workspace layout (float units) ----------------
#define OFF_QKVPTS ((size_t)0)         // [512][3456] f32 (only cols >=2304 written)
#define OFF_PBATTN ((size_t)1769472)   // [b][h][i][j] bf16 (pb+bias)
#define OFF_X1DB   ((size_t)3342336)   // [512][768] bf16 (dead after gemm1)
#define OFF_VT     OFF_X1DB            // [2][768][256] bf16 (overlay)
#define OFF_W1T    ((size_t)3538944)   // [3456][768] bf16 (dead after gemm1)
#define OFF_ABF    OFF_W1T             // [b][h][i][j] bf16 attn (overlay)
#define OFF_W2T    ((size_t)4866048)   // [768][2304] bf16
#define OFF_FEATB  ((size_t)5750784)   // [512][2304] bf16
#define OFF_QPTS   ((size_t)6340608)   // [b][h][i][24] f32
#define OFF_KPTS   ((size_t)6488064)   // [b][h][24][256] f32
#define OFF_QKHM   ((size_t)6635520)   // [2][2][12][256][64] bf16
#define OFF_VGJT   ((size_t)7028736)   // [2][576][256] bf16
#define OFF_WPVT   ((size_t)7176192)   // [768][128] bf16
// end = 7,225,344 f = 28.9 MB

#define SCALAR_W 0.07216878364870323f
#define POINT_W  0.13608276348795434f
#define PAIR_W   0.57735026918962576f

typedef __attribute__((ext_vector_type(8))) short short8;
typedef __attribute__((ext_vector_type(4))) short short4v;
typedef __attribute__((ext_vector_type(4))) float f32x4;

__device__ inline ushort f2bf(float f) {
  __hip_bfloat16 h = __float2bfloat16(f);
  return *reinterpret_cast<ushort*>(&h);
}
__device__ inline float bf2f(short u) {
  return __uint_as_float(((unsigned int)(unsigned short)u) << 16);
}

// ---------- merged prep: pairbias (1024) | convert_x (192) | 11 transposes (~4464) ----------
struct TJob { const float* src; ushort* dst; int K, N, sStride, dStride, nx, ny; };
struct TJobs { TJob j[11]; };

__global__ __launch_bounds__(256)
void prep_kernel(const float* __restrict__ x2d, const float* __restrict__ Wpb,
                 const float* __restrict__ bias, ushort* __restrict__ pbattn,
                 const float* __restrict__ x1d, ushort* __restrict__ x1db,
                 TJobs jobs) {
  __shared__ __align__(16) char smem[9216];
  const int blk = blockIdx.x;
  const int tid = threadIdx.x;
  if (blk < 1024) {
    // ---- pair-bias: MFMA, A direct from global x2d ----
    ushort* wpbT_s = (ushort*)smem;                 // 16*136*2 = 4352
    ushort* pb_s   = (ushort*)(smem + 4352);        // 128*18*2 = 4608
    const int bi = blk >> 1, half = blk & 1;
    const int b = bi >> 8, i = bi & 255;
    for (int u = tid; u < 2048; u += 256) {
      const int h = u >> 7, p = u & 127;
      wpbT_s[h * 136 + p] = (h < 12) ? f2bf(Wpb[p * 12 + h]) : (ushort)0;
    }
    __syncthreads();
    const int lane = tid & 63, w = tid >> 6;
    const int l15 = lane & 15, kq = lane >> 4;
    const float* xbase = x2d + ((size_t)bi * II + half * 128) * DPP;
#pragma unroll
    for (int mi = 0; mi < 2; ++mi) {
      const int mt = w + mi * 4;
      const int jl = mt * 16 + l15;
      const float* arow = xbase + (size_t)jl * DPP;
      f32x4 acc = {};
#pragma unroll
      for (int kk = 0; kk < 4; ++kk) {
        const float4 f0 = *reinterpret_cast<const float4*>(arow + kk * 32 + kq * 8);
        const float4 f1 = *reinterpret_cast<const float4*>(arow + kk * 32 + kq * 8 + 4);
        short8 af;
        af[0] = (short)f2bf(f0.x); af[1] = (short)f2bf(f0.y);
        af[2] = (short)f2bf(f0.z); af[3] = (short)f2bf(f0.w);
        af[4] = (short)f2bf(f1.x); af[5] = (short)f2bf(f1.y);
        af[6] = (short)f2bf(f1.z); af[7] = (short)f2bf(f1.w);
        const short8 bf = *reinterpret_cast<const short8*>(&wpbT_s[l15 * 136 + kk * 32 + kq * 8]);
        acc = __builtin_amdgcn_mfma_f32_16x16x32_bf16(af, bf, acc, 0, 0, 0);
      }
#pragma unroll
      for (int rr = 0; rr < 4; ++rr)
        pb_s[(mt * 16 + kq * 4 + rr) * 18 + l15] = f2bf(acc[rr]);
    }
    __syncthreads();
    if (tid < 192) {
      const int h = tid >> 4, jq = tid & 15;
      const int jl0 = jq * 8;
      const size_t base = (((size_t)(b * HH + h) * II + i) * II) + half * 128 + jl0;
      const float4 bv0 = *reinterpret_cast<const float4*>(bias + base);
      const float4 bv1 = *reinterpret_cast<const float4*>(bias + base + 4);
      const float bv[8] = {bv0.x, bv0.y, bv0.z, bv0.w, bv1.x, bv1.y, bv1.z, bv1.w};
      short8 o;
#pragma unroll
      for (int e = 0; e < 8; ++e)
        o[e] = (short)f2bf(PAIR_W * bf2f((short)pb_s[(jl0 + e) * 18 + h]) + bv[e]);
      *reinterpret_cast<short8*>(pbattn + base) = o;
    }
  } else if (blk < 1216) {
    // ---- x1d -> bf16 ----
    const int idx = (blk - 1024) * 256 + tid;
    if (idx < 512 * 768 / 8) {
      const float4 f0 = reinterpret_cast<const float4*>(x1d)[idx * 2 + 0];
      const float4 f1 = reinterpret_cast<const float4*>(x1d)[idx * 2 + 1];
      short8 v;
      v[0] = (short)f2bf(f0.x); v[1] = (short)f2bf(f0.y);
      v[2] = (short)f2bf(f0.z); v[3] = (short)f2bf(f0.w);
      v[4] = (short)f2bf(f1.x); v[5] = (short)f2bf(f1.y);
      v[6] = (short)f2bf(f1.z); v[7] = (short)f2bf(f1.w);
      reinterpret_cast<short8*>(x1db)[idx] = v;
    }
  } else {
    // ---- weight transpose jobs (flat-dispatched) ----
    float (*t)[33] = (float(*)[33])smem;            // 32*33*4 = 4224
    int blk2 = blk - 1216;
#pragma unroll 1
    for (int jj = 0; jj < 11; ++jj) {
      const TJob J = jobs.j[jj];
      const int cnt = J.nx * J.ny;
      if (blk2 < cnt) {
        const int n0 = (blk2 % J.nx) * 32, k0 = (blk2 / J.nx) * 32;
        const int c = tid & 31, r = tid >> 5;
#pragma unroll
        for (int u = 0; u < 4; ++u) {
          const int kk = r + u * 8;
          t[kk][c] = (n0 + c < J.N) ? J.src[(size_t)(k0 + kk) * J.sStride + n0 + c] : 0.f;
        }
        __syncthreads();
#pragma unroll
        for (int u = 0; u < 4; ++u) {
          const int n = n0 + r + u * 8;
          if (n < J.N) J.dst[(size_t)n * J.dStride + k0 + c] = f2bf(t[c][r + u * 8]);
        }
        return;
      }
      blk2 -= cnt;
    }
  }
}

// ---------- MFMA bf16 GEMM (gemm1: epilogue routing; gemm2: plain) ----------
__global__ __launch_bounds__(256)
void mfma_gemm_kernel(const ushort* __restrict__ A, const ushort* __restrict__ Bt,
                      float* __restrict__ C, const float* __restrict__ bias,
                      ushort* __restrict__ Cb, ushort* __restrict__ Vt, int N, int K) {
  __shared__ short a_s[64 * 64];
  __shared__ short b_s[64 * 64];
  const int tid = threadIdx.x;
  const int lane = tid & 63;
  const int wave = tid >> 6;
  const int wm = wave >> 1, wn = wave & 1;
  const int m0 = blockIdx.x * 64, n0 = blockIdx.y * 64;
  const int lrow = tid >> 3, lch = tid & 7;
  const int l15 = lane & 15, l7 = lane & 7, kq = lane >> 4;
  f32x4 acc[2][2] = {};
  for (int kc = 0; kc < K; kc += 64) {
#pragma unroll
    for (int u = 0; u < 2; ++u) {
      const int r = lrow + u * 32;
      const short8 av = *reinterpret_cast<const short8*>(A  + (size_t)(m0 + r) * K + kc + lch * 8);
      const short8 bv = *reinterpret_cast<const short8*>(Bt + (size_t)(n0 + r) * K + kc + lch * 8);
      const int sc = ((lch ^ (r & 7)) << 3);
      *reinterpret_cast<short8*>(&a_s[r * 64 + sc]) = av;
      *reinterpret_cast<short8*>(&b_s[r * 64 + sc]) = bv;
    }
    __syncthreads();
#pragma unroll
    for (int kk = 0; kk < 64; kk += 32) {
      const int ch = (kk >> 3) + kq;
      const int cx = ((ch ^ l7) << 3);
      short8 af[2], bf[2];
      af[0] = *reinterpret_cast<const short8*>(&a_s[(wm * 32 +      l15) * 64 + cx]);
      af[1] = *reinterpret_cast<const short8*>(&a_s[(wm * 32 + 16 + l15) * 64 + cx]);
      bf[0] = *reinterpret_cast<const short8*>(&b_s[(wn * 32 +      l15) * 64 + cx]);
      bf[1] = *reinterpret_cast<const short8*>(&b_s[(wn * 32 + 16 + l15) * 64 + cx]);
#pragma unroll
      for (int mt = 0; mt < 2; ++mt)
#pragma unroll
        for (int nt = 0; nt < 2; ++nt)
          acc[mt][nt] = __builtin_amdgcn_mfma_f32_16x16x32_bf16(af[mt], bf[nt], acc[mt][nt], 0, 0, 0);
    }
    __syncthreads();
  }
#pragma unroll
  for (int mt = 0; mt < 2; ++mt) {
    const int r0 = m0 + wm * 32 + mt * 16 + kq * 4;
#pragma unroll
    for (int nt = 0; nt < 2; ++nt) {
      const int c = n0 + wn * 32 + nt * 16 + l15;
      const float bv = bias ? bias[c] : 0.f;
#pragma unroll
      for (int rr = 0; rr < 4; ++rr) {
        const float val = acc[mt][nt][rr] + bv;
        const int m = r0 + rr;
        if (!Cb) {
          C[(size_t)m * N + c] = val;
        } else if (c < 1536) {
          const int bb = m >> 8, ii = m & 255;
          const int plane = (c >= 768) ? 1 : 0;
          const int hh = (c & 767) >> 6, cc2 = c & 63;
          Cb[((((size_t)plane * BB + bb) * HH + hh) * II + ii) * 64 + cc2] = f2bf(val);
        } else if (c < 2304) {
          const int bb = m >> 8, ii = m & 255;
          Vt[((size_t)bb * DD + (c - 1536)) * II + ii] = f2bf(val);
        } else {
          C[(size_t)m * N + c] = val;
        }
      }
    }
  }
}

// ---------- frame transforms ----------
struct XfJob { const float* T; const float* R; float* dstf; ushort* dstb;
               int np; int sub; int srccol; int mode; };
struct XfJobs { XfJob j[6]; };

__global__ __launch_bounds__(256)
void transform_kernel(const float* __restrict__ qkvpts, XfJobs jobs) {
  const XfJob J = jobs.j[blockIdx.y];
  const int idx = blockIdx.x * 256 + threadIdx.x;
  if (J.mode == 1) {
    const int hn = HH * J.np;
    if (idx >= BB * II * hn) return;
    const int bi = idx / hn, rem = idx - bi * hn;
    const float* p = qkvpts + (size_t)bi * NPACK + J.srccol + rem * 3;
    const float p0 = p[0], p1 = p[1], p2 = p[2];
    const float* R = J.R + (size_t)bi * 9;
    const float* T = J.T + (size_t)bi * 3;
    const float o0 = R[0] * p0 + R[3] * p1 + R[6] * p2 + T[0];
    const float o1 = R[1] * p0 + R[4] * p1 + R[7] * p2 + T[1];
    const float o2 = R[2] * p0 + R[5] * p1 + R[8] * p2 + T[2];
    const int h = rem / J.np, n = rem - h * J.np;
    const int b = bi >> 8, i = bi & 255;
    float* d = J.dstf + ((size_t)(b * HH + h) * II + i) * 24 + J.sub + n * 3;
    d[0] = o0; d[1] = o1; d[2] = o2;
  } else {
    if (idx >= BB * HH * J.np * II) return;
    const int i = idx & 255;
    int r2 = idx >> 8;
    const int n = r2 % J.np; r2 /= J.np;
    const int h = r2 % HH;
    const int b = r2 / HH;
    const int bi = b * II + i;
    const float* p = qkvpts + (size_t)bi * NPACK + J.srccol + (h * J.np + n) * 3;
    const float p0 = p[0], p1 = p[1], p2 = p[2];
    const float* R = J.R + (size_t)bi * 9;
    const float* T = J.T + (size_t)bi * 3;
    const float o0 = R[0] * p0 + R[3] * p1 + R[6] * p2 + T[0];
    const float o1 = R[1] * p0 + R[4] * p1 + R[7] * p2 + T[1];
    const float o2 = R[2] * p0 + R[5] * p1 + R[8] * p2 + T[2];
    if (J.mode == 2) {
      const int col = J.sub + h * 24 + n * 3;
      ushort* d = J.dstb + ((size_t)b * 576 + col) * II + i;
      d[0] = f2bf(o0); d[II] = f2bf(o1); d[2 * II] = f2bf(o2);
    } else {
      float* d = J.dstf + ((size_t)(b * HH + h) * 24 + J.sub + n * 3) * II + i;
      d[0] = o0; d[II] = o1; d[2 * II] = o2;
    }
  }
}

// ---------- fused attention ----------
__global__ __launch_bounds__(256)
void attn_kernel(const ushort* __restrict__ qkhm,
                 const float* __restrict__ qpts, const float* __restrict__ kpts,
                 const float* __restrict__ tpw_past, const float* __restrict__ tpw_last,
                 const ushort* __restrict__ pbattn, ushort* __restrict__ abf) {
  __shared__ float qp_s[16 * 24];
  __shared__ float pb_s[16 * 260];
  __shared__ float red_s[2][16 * 4];
  __shared__ ushort a_lds[16 * 264];
  const int tid = threadIdx.x;
  const int lane = tid & 63;
  const int w = tid >> 6;
  const int i0 = blockIdx.x * 16;
  const int h = blockIdx.y;
  const int b = blockIdx.z;
  const size_t bh = (size_t)b * HH + h;
  if (tid < 96)
    reinterpret_cast<float4*>(qp_s)[tid] =
        reinterpret_cast<const float4*>(qpts + (bh * II + i0) * 24)[tid];
  {
    const ushort* src = pbattn + (bh * II + i0) * II;
    for (int u = tid; u < 512; u += 256) {
      const int r = u >> 5, c8 = u & 31;
      const short8 v = *reinterpret_cast<const short8*>(src + (size_t)r * II + c8 * 8);
      float* d = &pb_s[r * 260 + c8 * 8];
#pragma unroll
      for (int e = 0; e < 8; ++e) d[e] = bf2f(v[e]);
    }
  }
  __syncthreads();
  const int l15 = lane & 15, kq = lane >> 4;
  const ushort* qrow = qkhm + (((size_t)b * HH + h) * II + i0 + l15) * 64;
  const ushort* kplane = qkhm + (((size_t)(BB + b) * HH + h) * II) * 64;
  const short8 af0 = *reinterpret_cast<const short8*>(qrow + kq * 8);
  const short8 af1 = *reinterpret_cast<const short8*>(qrow + 32 + kq * 8);
  const float pwp = 0.5f * POINT_W * log1pf(expf(tpw_past[h]));
  const float pwl = 0.5f * POINT_W * log1pf(expf(tpw_last[h]));
  const float* kpt = kpts + bh * 6144;
  float lg[4][4];
#pragma unroll
  for (int jb = 0; jb < 4; ++jb) {
    const int j = w * 64 + jb * 16 + l15;
    const ushort* krow = kplane + (size_t)j * 64;
    f32x4 acc = {};
    acc = __builtin_amdgcn_mfma_f32_16x16x32_bf16(
        af0, *reinterpret_cast<const short8*>(krow + kq * 8), acc, 0, 0, 0);
    acc = __builtin_amdgcn_mfma_f32_16x16x32_bf16(
        af1, *reinterpret_cast<const short8*>(krow + 32 + kq * 8), acc, 0, 0, 0);
    float kg[24];
#pragma unroll
    for (int c = 0; c < 24; ++c) kg[c] = kpt[c * 256 + j];
#pragma unroll
    for (int rr = 0; rr < 4; ++rr) {
      const int il = kq * 4 + rr;
      const float* qg = &qp_s[il * 24];
      float dp = 0.f, dl = 0.f;
#pragma unroll
      for (int n = 0; n < 4; ++n) {
        float dx = qg[n * 3] - kg[n * 3], dy = qg[n * 3 + 1] - kg[n * 3 + 1],
              dz = qg[n * 3 + 2] - kg[n * 3 + 2];
        dp += sqrtf(dx * dx + dy * dy + dz * dz);
        dx = qg[12 + n * 3] - kg[12 + n * 3]; dy = qg[12 + n * 3 + 1] - kg[12 + n * 3 + 1];
        dz = qg[12 + n * 3 + 2] - kg[12 + n * 3 + 2];
        dl += sqrtf(dx * dx + dy * dy + dz * dz);
      }
      lg[jb][rr] = SCALAR_W * acc[rr] - pwp * dp - pwl * dl + pb_s[il * 260 + j];
    }
  }
#pragma unroll
  for (int rr = 0; rr < 4; ++rr) {
    float m = fmaxf(fmaxf(lg[0][rr], lg[1][rr]), fmaxf(lg[2][rr], lg[3][rr]));
    m = fmaxf(m, __shfl_xor(m, 1));
    m = fmaxf(m, __shfl_xor(m, 2));
    m = fmaxf(m, __shfl_xor(m, 4));
    m = fmaxf(m, __shfl_xor(m, 8));
    if (l15 == 0) red_s[0][(kq * 4 + rr) * 4 + w] = m;
  }
  __syncthreads();
#pragma unroll
  for (int rr = 0; rr < 4; ++rr) {
    const int il = kq * 4 + rr;
    const float* r = &red_s[0][il * 4];
    const float m = fmaxf(fmaxf(r[0], r[1]), fmaxf(r[2], r[3]));
    float s = 0.f;
#pragma unroll
    for (int jb = 0; jb < 4; ++jb) { lg[jb][rr] = __expf(lg[jb][rr] - m); s += lg[jb][rr]; }
    s += __shfl_xor(s, 1); s += __shfl_xor(s, 2);
    s += __shfl_xor(s, 4); s += __shfl_xor(s, 8);
    if (l15 == 0) red_s[1][il * 4 + w] = s;
  }
  __syncthreads();
#pragma unroll
  for (int rr = 0; rr < 4; ++rr) {
    const int il = kq * 4 + rr;
    const float* r = &red_s[1][il * 4];
    const float inv = 1.f / (r[0] + r[1] + r[2] + r[3]);
#pragma unroll
    for (int jb = 0; jb < 4; ++jb)
      a_lds[il * 264 + w * 64 + jb * 16 + l15] = f2bf(lg[jb][rr] * inv);
  }
  __syncthreads();
  ushort* ab = abf + (bh * II + i0) * II;
#pragma unroll
  for (int u = 0; u < 2; ++u) {
    const int idx = tid + u * 256;
    const int r = idx >> 5, cc = idx & 31;
    *reinterpret_cast<short8*>(ab + (size_t)r * II + cc * 8) =
        *reinterpret_cast<const short8*>(&a_lds[r * 264 + cc * 8]);
  }
}

// ---------- merged wpair (512 blocks) + av (192 blocks) ----------
__global__ __launch_bounds__(256)
void wpair_av_kernel(const float* __restrict__ x2d, const ushort* __restrict__ abf,
                     const ushort* __restrict__ wpvt,
                     const ushort* __restrict__ vt, const ushort* __restrict__ vgjt,
                     const float* __restrict__ past_T, const float* __restrict__ past_R,
                     ushort* __restrict__ featb) {
  __shared__ __align__(16) char smem[33792];
  const int blk = blockIdx.x;
  const int tid = threadIdx.x;
  const int lane = tid & 63, w = tid >> 6;
  const int l15 = lane & 15, kq = lane >> 4;
  if (blk < 512) {
    // ---- wpair: in-LDS transpose of x2d, MFMA, then @ WpvT ----
    ushort* a_s = (ushort*)smem;                       // 8192
    ushort* tb  = (ushort*)(smem + 8192);              // 17408
    float*  t_s = (float*)(smem + 25600);              // 8192
    const int bi = blk;
    const int b = bi >> 8, i = bi & 255;
#pragma unroll
    for (int u = 0; u < 2; ++u) {
      const int c = tid + u * 256;
      const int h = c >> 5, ch = c & 31;
      short8 v = {};
      if (h < 12)
        v = *reinterpret_cast<const short8*>(abf + (((size_t)(b * HH + h) * II + i) * II) + ch * 8);
      *reinterpret_cast<short8*>(&a_s[h * 256 + ((ch ^ h) << 3)]) = v;
    }
    const int n0 = w * 32;
    f32x4 acc[2] = {};
    for (int jt = 0; jt < 4; ++jt) {
      __syncthreads();
      const float4* src = reinterpret_cast<const float4*>(x2d + ((size_t)bi * II + jt * 64) * DPP);
#pragma unroll
      for (int u = 0; u < 8; ++u) {
        const int fid = tid + u * 256;
        const int j = fid >> 5, p4 = (fid & 31) * 4;
        const float4 v = src[fid];
        short4v o;
        o[0] = (short)f2bf(v.x); o[1] = (short)f2bf(v.y);
        o[2] = (short)f2bf(v.z); o[3] = (short)f2bf(v.w);
        *reinterpret_cast<short4v*>(&tb[j * 136 + (p4 ^ ((j >> 3) << 4))]) = o;
      }
      __syncthreads();
#pragma unroll
      for (int nt = 0; nt < 2; ++nt) {
        const int p = n0 + nt * 16 + l15;
#pragma unroll
        for (int kk = 0; kk < 2; ++kk) {
          const int ch32 = jt * 8 + kk * 4 + kq;
          const short8 af = *reinterpret_cast<const short8*>(&a_s[l15 * 256 + ((ch32 ^ l15) << 3)]);
          short8 bf;
#pragma unroll
          for (int e = 0; e < 8; ++e) {
            const int row = kk * 32 + kq * 8 + e;
            bf[e] = (short)tb[row * 136 + (p ^ ((row >> 3) << 4))];
          }
          acc[nt] = __builtin_amdgcn_mfma_f32_16x16x32_bf16(af, bf, acc[nt], 0, 0, 0);
        }
      }
    }
#pragma unroll
    for (int nt = 0; nt < 2; ++nt) {
      const int p = n0 + nt * 16 + l15;
#pragma unroll
      for (int r = 0; r < 4; ++r) t_s[(kq * 4 + r) * 128 + p] = acc[nt][r];
    }
    __syncthreads();
    ushort* fout = featb + (size_t)bi * FEAT_DIM;
#pragma unroll
    for (int u = 0; u < 3; ++u) {
      const int c = tid + u * 256;
      const int h = c >> 6;
      const ushort* wr = wpvt + (size_t)c * DPP;
      float o = 0.f;
      for (int p = 0; p < DPP; p += 8) {
        const short8 wv = *reinterpret_cast<const short8*>(wr + p);
#pragma unroll
        for (int e = 0; e < 8; ++e) o += t_s[h * 128 + p + e] * bf2f(wv[e]);
      }
      fout[c] = f2bf(o);
    }
  } else {
    // ---- av: attn @ [v | og_past | og_last] + inverse transform ----
    ushort* a_s = (ushort*)smem;                       // 16384
    float*  c_s = (float*)(smem + 16384);              // 32*116*4 = 14848
    const int blk2 = blk - 512;
    const int it = blk2 & 7;
    const int rest = blk2 >> 3;
    const int h = rest % 12;
    const int b = rest / 12;
    const int i0 = it * 32;
    const size_t bh = (size_t)b * HH + h;
    {
      const ushort* src = abf + (bh * II + i0) * II;
#pragma unroll
      for (int u = 0; u < 4; ++u) {
        const int cidx = tid + u * 256;
        const int r = cidx >> 5, ch = cidx & 31;
        const short8 v = *reinterpret_cast<const short8*>(src + (size_t)r * II + ch * 8);
        *reinterpret_cast<short8*>(&a_s[r * 256 + ((ch ^ (r & 7)) << 3)]) = v;
      }
    }
    __syncthreads();
    for (int t = w; t < 14; t += 4) {
      const int mt = t / 7, nt = t % 7;
      const int c = nt * 16 + l15;
      const ushort* bcol;
      if (c < 64)      bcol = vt   + ((size_t)b * DD + h * 64 + c) * II;
      else if (c < 88) bcol = vgjt + ((size_t)b * 576 + h * 24 + (c - 64)) * II;
      else             bcol = vgjt + ((size_t)b * 576 + 288 + h * 24 + (c - 88)) * II;
      f32x4 acc = {};
#pragma unroll
      for (int ks = 0; ks < 8; ++ks) {
        const int ch = ks * 4 + kq;
        const int r = mt * 16 + l15;
        const short8 af = *reinterpret_cast<const short8*>(&a_s[r * 256 + ((ch ^ (r & 7)) << 3)]);
        const short8 bf = *reinterpret_cast<const short8*>(bcol + ks * 32 + kq * 8);
        acc = __builtin_amdgcn_mfma_f32_16x16x32_bf16(af, bf, acc, 0, 0, 0);
      }
#pragma unroll
      for (int rr = 0; rr < 4; ++rr) c_s[(mt * 16 + kq * 4 + rr) * 116 + c] = acc[rr];
    }
    __syncthreads();
    {
      const int il = tid >> 3, c0 = (tid & 7) * 8;
      ushort* fo = featb + (size_t)(b * II + i0 + il) * FEAT_DIM + 768 + h * 64 + c0;
      short8 o;
#pragma unroll
      for (int e = 0; e < 8; ++e) o[e] = (short)f2bf(c_s[il * 116 + c0 + e]);
      *reinterpret_cast<short8*>(fo) = o;
    }
    for (int u = tid; u < 512; u += 256) {
      const int il = u >> 4;
      const int br = (u >> 3) & 1;
      const int n = u & 7;
      const int bi = b * II + i0 + il;
      const float* T = past_T + (size_t)bi * 3;
      const float* R = past_R + (size_t)bi * 9;
      const int cb = 64 + br * 24 + n * 3;
      const float o0 = c_s[il * 116 + cb + 0] - T[0];
      const float o1 = c_s[il * 116 + cb + 1] - T[1];
      const float o2 = c_s[il * 116 + cb + 2] - T[2];
      const float l0 = R[0] * o0 + R[1] * o1 + R[2] * o2;
      const float l1 = R[3] * o0 + R[4] * o1 + R[5] * o2;
      const float l2 = R[6] * o0 + R[7] * o1 + R[8] * o2;
      const float nn = sqrtf(l0 * l0 + l1 * l1 + l2 * l2);
      const int r = h * 8 + n;
      ushort* fout = featb + (size_t)bi * FEAT_DIM;
      const int olbase = br ? 1920 : 1536;
      const int nbase  = br ? 2208 : 1824;
      fout[olbase + r * 3 + 0] = f2bf(l0);
      fout[olbase + r * 3 + 1] = f2bf(l1);
      fout[olbase + r * 3 + 2] = f2bf(l2);
      fout[nbase + r] = f2bf(nn);
    }
  }
}

extern "C" void kernel_launch(void* const* d_in, const int* in_sizes, int n_in,
                              void* d_out, int out_size, void* d_ws, size_t ws_size,
                              hipStream_t stream) {
  (void)in_sizes; (void)n_in; (void)out_size; (void)ws_size;
  const float* x1d      = (const float*)d_in[0];
  const float* x2d      = (const float*)d_in[1];
  const float* past_T   = (const float*)d_in[2];
  const float* past_R   = (const float*)d_in[3];
  const float* last_T   = (const float*)d_in[4];
  const float* last_R   = (const float*)d_in[5];
  const float* bias     = (const float*)d_in[6];
  const float* Wq       = (const float*)d_in[7];
  const float* Wk       = (const float*)d_in[8];
  const float* Wv       = (const float*)d_in[9];
  const float* Wpb      = (const float*)d_in[10];
  const float* Wpq_past = (const float*)d_in[11];
  const float* Wpk_past = (const float*)d_in[12];
  const float* Wpv_past = (const float*)d_in[13];
  const float* Wpq_last = (const float*)d_in[14];
  const float* Wpk_last = (const float*)d_in[15];
  const float* Wpv_last = (const float*)d_in[16];
  const float* tpw_past = (const float*)d_in[17];
  const float* tpw_last = (const float*)d_in[18];
  const float* W_pair_value = (const float*)d_in[19];
  const float* W_out    = (const float*)d_in[20];
  const float* b_out    = (const float*)d_in[21];
  float* out = (float*)d_out;
  float* ws  = (float*)d_ws;

  float*  qkvpts = ws + OFF_QKVPTS;
  ushort* pbattn = (ushort*)(ws + OFF_PBATTN);
  ushort* x1db   = (ushort*)(ws + OFF_X1DB);
  ushort* vt     = (ushort*)(ws + OFF_VT);
  ushort* w1t    = (ushort*)(ws + OFF_W1T);
  ushort* abf    = (ushort*)(ws + OFF_ABF);
  ushort* w2t    = (ushort*)(ws + OFF_W2T);
  ushort* featb  = (ushort*)(ws + OFF_FEATB);
  float*  qpts   = ws + OFF_QPTS;
  float*  kpts   = ws + OFF_KPTS;
  ushort* qkhm   = (ushort*)(ws + OFF_QKHM);
  ushort* vgjt   = (ushort*)(ws + OFF_VGJT);
  ushort* wpvt   = (ushort*)(ws + OFF_WPVT);

  const dim3 blk256(256);

  // 1) merged prep: pairbias | x1d->bf16 | 11 weight transposes, one launch
  {
    TJobs jobs = {};
    // nx = ceil(N/32), ny = ceil(K/32)
    jobs.j[0]  = {Wq,       w1t + (size_t)   0 * 768, DD,      DD,   DD,  768,  24, 24};
    jobs.j[1]  = {Wk,       w1t + (size_t) 768 * 768, DD,      DD,   DD,  768,  24, 24};
    jobs.j[2]  = {Wv,       w1t + (size_t)1536 * 768, DD,      DD,   DD,  768,  24, 24};
    jobs.j[3]  = {Wpq_past, w1t + (size_t)2304 * 768, DD,     144,   144, 768,   5, 24};
    jobs.j[4]  = {Wpk_past, w1t + (size_t)2448 * 768, DD,     144,   144, 768,   5, 24};
    jobs.j[5]  = {Wpv_past, w1t + (size_t)2592 * 768, DD,     288,   288, 768,   9, 24};
    jobs.j[6]  = {Wpq_last, w1t + (size_t)2880 * 768, DD,     144,   144, 768,   5, 24};
    jobs.j[7]  = {Wpk_last, w1t + (size_t)3024 * 768, DD,     144,   144, 768,   5, 24};
    jobs.j[8]  = {Wpv_last, w1t + (size_t)3168 * 768, DD,     288,   288, 768,   9, 24};
    jobs.j[9]  = {W_out,    w2t,                      FEAT_DIM, DD,  DD,  2304, 24, 72};
    jobs.j[10] = {W_pair_value, wpvt,                 DPP,     DD,   DD,  DPP,  24,  4};
    int tblocks = 0;
    for (int j = 0; j < 11; ++j) tblocks += jobs.j[j].nx * jobs.j[j].ny;
    prep_kernel<<<dim3(1216 + tblocks), blk256, 0, stream>>>(
        x2d, Wpb, bias, pbattn, x1d, x1db, jobs);
  }

  // 2) fused GEMM: qk -> qkhm, v -> vt, points -> qkvpts f32
  mfma_gemm_kernel<<<dim3(8, 54), blk256, 0, stream>>>(
      x1db, w1t, qkvpts, nullptr, qkhm, vt, NPACK, DD);

  // 3) frame transforms
  {
    XfJobs jobs = {};
    jobs.j[0] = {past_T, past_R, qpts, nullptr, NPQ,   0, 2304, 1};
    jobs.j[1] = {past_T, past_R, kpts, nullptr, NPQ,   0, 2448, 3};
    jobs.j[2] = {past_T, past_R, nullptr, vgjt, NPV,   0, 2592, 2};
    jobs.j[3] = {last_T, last_R, qpts, nullptr, NPQ,  12, 2880, 1};
    jobs.j[4] = {last_T, last_R, kpts, nullptr, NPQ,  12, 3024, 3};
    jobs.j[5] = {last_T, last_R, nullptr, vgjt, NPV, 288, 3168, 2};
    transform_kernel<<<dim3(192, 6), blk256, 0, stream>>>(qkvpts, jobs);
  }

  // 4) fused attention
  attn_kernel<<<dim3(16, HH, BB), blk256, 0, stream>>>(
      qkhm, qpts, kpts, tpw_past, tpw_last, pbattn, abf);

  // 5) merged wpair + av (single launch, 704 blocks)
  wpair_av_kernel<<<dim3(704), blk256, 0, stream>>>(
      x2d, abf, wpvt, vt, vgjt, past_T, past_R, featb);

  // 6) out = feat @ W_out + b_out
  mfma_gemm_kernel<<<dim3(8, 12), blk256, 0, stream>>>(
      featb, w2t, out, b_out, nullptr, nullptr, DD, FEAT_DIM);
}